// Round 10
// baseline (265.717 us; speedup 1.0000x reference)
//
#include <hip/hip_runtime.h>
#include <hip/hip_bf16.h>
#include <math.h>

#define B_ 4
#define F_ 256
#define C_ 19
#define S_ 256
#define N_ 16384
#define M_ 9728
#define MT_ 38           // m-tiles (256 cols each) in pass1
#define NP_ 18816        // totpart slot capacity (>= any padded_total)
#define PREP_PRED 256
#define PREP_TOTAL 2688  // 256 pred + 2432 mem
#define GEMM_BLKS 512
#define P2_BLOCKS (C_ * 16)

typedef __bf16 bf16_t;
typedef bf16_t bf16x8 __attribute__((ext_vector_type(8)));
typedef float floatx4 __attribute__((ext_vector_type(4)));

#define AS1 __attribute__((address_space(1)))
#define AS3 __attribute__((address_space(3)))

// Fragment-order layout: element (row, f) lives at
//   ((row>>4)*8 + (f>>5))*512 + ((f>>3)&3)*128 + (row&15)*8 + (f&7)
// For 64-aligned panels this equals panel_base*256 + 8*k with k the linear
// 16B-chunk index -> global_load_lds can stage panels linearly.
__device__ inline size_t fragoff(int row, int f) {
    return ((size_t)((row >> 4) * 8 + (f >> 5))) * 512
         + (size_t)((((f >> 3) & 3) * 128) + ((row & 15) * 8) + (f & 7));
}

// ---------------- kernel 0: bucketing + inverse slot map ----------
// ctrl zeroed by hipMemsetAsync before this kernel.
__global__ __launch_bounds__(256) void k_bucket(const int* __restrict__ labels,
                                                const int* __restrict__ mask,
                                                int* __restrict__ ccnt,
                                                int* __restrict__ pix,
                                                int* __restrict__ slotmap) {
    __shared__ int hist[C_], base_s[C_], cur[C_];
    int t = threadIdx.x;
    int n0 = blockIdx.x * 256;
    if (t < C_) { hist[t] = 0; cur[t] = 0; }
    __syncthreads();
    int myc = labels[n0 + t];
    int mym = mask[n0 + t];
    if (mym) atomicAdd(&hist[myc], 1);
    __syncthreads();
    if (t < C_) base_s[t] = atomicAdd(&ccnt[t], hist[t]);
    __syncthreads();
    int sm = -1;
    if (mym) {
        int o = atomicAdd(&cur[myc], 1);
        int pos = base_s[myc] + o;
        pix[myc * N_ + pos] = n0 + t;
        sm = (myc << 16) | pos;
    }
    slotmap[n0 + t] = sm;
}

// ---------------- kernel 1: prep -> compact A16c (masked only, 64-padded) + B16 ----------
// B16 entries scaled by 2.0 (exact in bf16): acc = 2*cos directly, so the
// epilogue exp is __expf(acc) with no runtime scale mul.
__global__ __launch_bounds__(256) void k_prep(const float* __restrict__ pred,
                                              const float* __restrict__ mem,
                                              __hip_bfloat16* __restrict__ A16c,
                                              __hip_bfloat16* __restrict__ B16,
                                              const int* __restrict__ ccnt,
                                              const int* __restrict__ slotmap) {
    int bid = blockIdx.x;
    int t = threadIdx.x;
    if (bid < PREP_PRED) {
        __shared__ float part[4][64];
        __shared__ float invf_s[64];
        __shared__ int pre_s[C_];
        int b = bid >> 6, hw0 = (bid & 63) * 64;
        int j = t & 63, q = t >> 6;
        int n0 = b * 4096 + hw0;

        if (t < C_) {                       // 64-padded class prefix (ccnt final)
            int pre = 0;
            for (int cc = 0; cc < t; ++cc) pre += (ccnt[cc] + 63) & ~63;
            pre_s[t] = pre;
        }

        const float* base = pred + ((size_t)b * F_ + q * 64) * 4096 + hw0 + j;
        float v[64];
        float s = 0.f;
        #pragma unroll
        for (int i = 0; i < 64; ++i) {
            float x = base[(size_t)i * 4096];
            v[i] = x;
            s += x * x;
        }
        part[q][j] = s;
        __syncthreads();
        if (t < 64) invf_s[t] = 1.0f / sqrtf(part[0][t] + part[1][t] + part[2][t] + part[3][t]);
        __syncthreads();
        int sm = slotmap[n0 + j];
        if (sm >= 0) {
            int slot = pre_s[sm >> 16] + (sm & 0xffff);
            float invf = invf_s[j];
            #pragma unroll
            for (int c = 0; c < 8; ++c) {
                int f = q * 64 + c * 8;
                __hip_bfloat16 tmp[8];
                #pragma unroll
                for (int u = 0; u < 8; ++u) tmp[u] = __float2bfloat16(v[c * 8 + u] * invf);
                *(float4*)&A16c[fragoff(slot, f)] = *(float4*)tmp;
            }
        }
    } else {
        int row  = (bid - PREP_PRED) * 4 + (t >> 6);
        int lane = t & 63;
        float4 a = ((const float4*)(mem + (size_t)row * F_))[lane];
        float s = a.x*a.x + a.y*a.y + a.z*a.z + a.w*a.w;
        #pragma unroll
        for (int off = 32; off; off >>= 1) s += __shfl_xor(s, off, 64);
        float invm = 2.0f / sqrtf(s);          // fold exp scale (exact in bf16)
        __hip_bfloat16 tmp[4];
        tmp[0] = __float2bfloat16(a.x * invm);
        tmp[1] = __float2bfloat16(a.y * invm);
        tmp[2] = __float2bfloat16(a.z * invm);
        tmp[3] = __float2bfloat16(a.w * invm);
        *(float2*)&B16[fragoff(row, lane * 4)] = *(float2*)tmp;
    }
}

// ---------------- kernel 2: pass-1 GEMM, fully barrier-free mt loop ----------
// Each wave (nh,mq) writes its own 64 row-sums straight to global
// totpart4[mt*4+mq][slot0+nh*64+..] -> zero intra-block sync after A-stage.
// Waves desync -> load/MFMA/exp phases of the 4 waves/SIMD interleave,
// overlapping MFMA and VALU pipes (the per-mt barrier was phase-aligning
// them: MfmaUtil 29% == MFMA-phase fraction of the wave cycle).
__global__ __launch_bounds__(512, 4) void k_pass1(const __hip_bfloat16* __restrict__ A16c,
                                                  const __hip_bfloat16* __restrict__ B16,
                                                  const int* __restrict__ ccnt,
                                                  float* __restrict__ totpart4) {
    __shared__ __hip_bfloat16 As[128 * 256];     // 64 KB
    int bid = blockIdx.x;
    int t = threadIdx.x;
    int w = t >> 6, lane = t & 63;
    int nh = w & 1, mq = w >> 1;

    int padded_total = 0;
    #pragma unroll
    for (int cc = 0; cc < C_; ++cc) padded_total += (ccnt[cc] + 63) & ~63;
    int nt_total = (padded_total + 127) >> 7;
    if (nt_total == 0) return;
    int nchunk = GEMM_BLKS / nt_total;
    if (nchunk > MT_) nchunk = MT_;
    if (nchunk < 1) nchunk = 1;
    if (bid >= nt_total * nchunk) return;
    int panel = bid % nt_total;
    int chunk = bid / nt_total;
    int slot0 = panel << 7;
    int mt_lo = (chunk * MT_) / nchunk;
    int mt_hi = ((chunk + 1) * MT_) / nchunk;

    // stage A panel: 64 KB linear from compact buffer
    {
        const __hip_bfloat16* src = A16c + ((size_t)slot0 << 8) + w * 4096 + lane * 8;
        __hip_bfloat16* dst = &As[w * 4096];
        #pragma unroll
        for (int i = 0; i < 8; ++i)
            __builtin_amdgcn_global_load_lds((const AS1 unsigned int*)(src + i * 512),
                                             (AS3 unsigned int*)(dst + i * 512), 16, 0, 0);
    }
    __syncthreads();

    int colL = lane & 15, rgrp = (lane >> 4) * 4;
    for (int mt = mt_lo; mt < mt_hi; ++mt) {
        floatx4 acc[4][4];
        #pragma unroll
        for (int i = 0; i < 4; ++i)
            #pragma unroll
            for (int j2 = 0; j2 < 4; ++j2) acc[i][j2] = (floatx4){0.f, 0.f, 0.f, 0.f};

        const bf16x8* Bp = (const bf16x8*)B16 + ((size_t)(mt * 16 + mq * 4) * 8) * 64 + lane;

        #pragma unroll
        for (int kt = 0; kt < 8; ++kt) {
            bf16x8 af[4], bfr[4];
            #pragma unroll
            for (int ni = 0; ni < 4; ++ni)
                af[ni] = *(const bf16x8*)&As[((nh * 4 + ni) * 8 + kt) * 512 + lane * 8];
            #pragma unroll
            for (int mi = 0; mi < 4; ++mi)
                bfr[mi] = Bp[(size_t)(mi * 8 + kt) * 64];
            __builtin_amdgcn_s_setprio(1);
            #pragma unroll
            for (int ni = 0; ni < 4; ++ni)
                #pragma unroll
                for (int mi = 0; mi < 4; ++mi)
                    acc[ni][mi] = __builtin_amdgcn_mfma_f32_16x16x32_bf16(af[ni], bfr[mi], acc[ni][mi], 0, 0, 0);
            __builtin_amdgcn_s_setprio(0);
        }

        // epilogue: E = exp(acc) (scale folded into B) -> per-wave row sums
        float racc[4][4];
        #pragma unroll
        for (int ni = 0; ni < 4; ++ni)
            #pragma unroll
            for (int r = 0; r < 4; ++r) racc[ni][r] = 0.f;
        #pragma unroll
        for (int ni = 0; ni < 4; ++ni)
            #pragma unroll
            for (int mi = 0; mi < 4; ++mi)
                #pragma unroll
                for (int r = 0; r < 4; ++r)
                    racc[ni][r] += __expf(acc[ni][mi][r]);

        float* outp = totpart4 + (size_t)(mt * 4 + mq) * NP_ + slot0 + nh * 64;
        #pragma unroll
        for (int ni = 0; ni < 4; ++ni)
            #pragma unroll
            for (int r = 0; r < 4; ++r) {
                float s = racc[ni][r];
                s += __shfl_xor(s, 1, 64);
                s += __shfl_xor(s, 2, 64);
                s += __shfl_xor(s, 4, 64);
                s += __shfl_xor(s, 8, 64);
                if (colL == 0) outp[ni * 16 + rgrp + r] = s;
            }
        // no barrier: next mt immediately; waves run free
    }
}

// ---------------- kernel 3: pass-2 own-class recompute + terms + final ----------------
__global__ __launch_bounds__(512) void k_pass2(const __hip_bfloat16* __restrict__ A16c,
                                               const __hip_bfloat16* __restrict__ B16,
                                               const int* __restrict__ ccnt,
                                               const int* __restrict__ pix,
                                               const float* __restrict__ totpart4,
                                               const int* __restrict__ wmem,
                                               float* __restrict__ class_sum,
                                               int* __restrict__ done,
                                               float* __restrict__ out) {
    __shared__ __hip_bfloat16 As[64 * 256];   // 32 KB, fragment order
    __shared__ float tot_s[64];
    __shared__ int wm_s[64];
    __shared__ float bsum_s[8][64];
    __shared__ float wsum_s[8][64];
    __shared__ float down_s[64];
    __shared__ float term_s[64];

    int c = blockIdx.x, tile = blockIdx.y;
    int cnt = ccnt[c];
    int t = threadIdx.x, ws = t >> 6, lane = t & 63;

    if (tile * 64 >= cnt) {                    // empty tile: still hit the counter
        if (t == 0) {
            __threadfence();
            int old = atomicAdd(done, 1);
            if (old == P2_BLOCKS - 1) {
                float loss = 0.f, kc = 0.f;
                for (int cc = 0; cc < C_; ++cc) {
                    int cn = ccnt[cc];
                    float sc = atomicAdd(&class_sum[cc], 0.f);
                    if (cn > 0) { loss += sc / ((float)cn * (float)S_); kc += 1.f; }
                }
                out[0] = loss / fmaxf(kc, 1.f);
            }
        }
        return;
    }

    // compact-slot base (64-padded prefix) of this tile
    int pre = 0;
    #pragma unroll
    for (int cc = 0; cc < C_; ++cc) if (cc < c) pre += (ccnt[cc] + 63) & ~63;
    int slot0 = pre + tile * 64;

    // stage A tile: 32 KB linear from compact buffer (issued first, overlaps
    // the scattered wmem/totpart reads below)
    {
        const __hip_bfloat16* src = A16c + ((size_t)slot0 << 8) + t * 8;
        __hip_bfloat16* dst = &As[t * 8];
        #pragma unroll
        for (int i = 0; i < 4; ++i)
            __builtin_amdgcn_global_load_lds((const AS1 unsigned int*)(src + i * 4096),
                                             (AS3 unsigned int*)(dst + i * 4096), 16, 0, 0);
    }

    if (t < 64) {
        int i = tile * 64 + t;
        int p = pix[c * N_ + (i < cnt ? i : 0)];
        wm_s[t] = wmem[p];
    }

    // inline total: 8 threads per pixel sum the 152 partial slots (contiguous)
    {
        int px = t >> 3, g = t & 7;
        float s = 0.f;
        for (int i = g; i < MT_ * 4; i += 8) s += totpart4[(size_t)i * NP_ + slot0 + px];
        s += __shfl_xor(s, 1, 64);
        s += __shfl_xor(s, 2, 64);
        s += __shfl_xor(s, 4, 64);
        if (g == 0) tot_s[px] = s;
    }
    __syncthreads();

    floatx4 acc[4][4];
    #pragma unroll
    for (int i = 0; i < 4; ++i)
        #pragma unroll
        for (int j = 0; j < 4; ++j) acc[i][j] = (floatx4){0.f, 0.f, 0.f, 0.f};

    const bf16x8* Bp = (const bf16x8*)B16 + ((size_t)(c * 32 + ws * 4) * 8) * 64 + lane;
    #pragma unroll
    for (int kt = 0; kt < 8; ++kt) {
        bf16x8 af[4], bfr[4];
        #pragma unroll
        for (int ni = 0; ni < 4; ++ni)
            af[ni] = *(const bf16x8*)&As[(ni * 8 + kt) * 512 + lane * 8];
        #pragma unroll
        for (int mi = 0; mi < 4; ++mi) bfr[mi] = Bp[(size_t)(mi * 8 + kt) * 64];
        #pragma unroll
        for (int ni = 0; ni < 4; ++ni)
            #pragma unroll
            for (int mi = 0; mi < 4; ++mi)
                acc[ni][mi] = __builtin_amdgcn_mfma_f32_16x16x32_bf16(af[ni], bfr[mi], acc[ni][mi], 0, 0, 0);
    }

    int colL = lane & 15, rgrp = (lane >> 4) * 4;
    float Ev[4][4][4];
    #pragma unroll
    for (int ni = 0; ni < 4; ++ni)
        #pragma unroll
        for (int mi = 0; mi < 4; ++mi)
            #pragma unroll
            for (int r = 0; r < 4; ++r)
                Ev[ni][mi][r] = __expf(acc[ni][mi][r]);

    #pragma unroll
    for (int ni = 0; ni < 4; ++ni)
        #pragma unroll
        for (int r = 0; r < 4; ++r) {
            float s = Ev[ni][0][r] + Ev[ni][1][r] + Ev[ni][2][r] + Ev[ni][3][r];
            s += __shfl_xor(s, 1, 64);
            s += __shfl_xor(s, 2, 64);
            s += __shfl_xor(s, 4, 64);
            s += __shfl_xor(s, 8, 64);
            if (colL == 0) bsum_s[ws][ni * 16 + rgrp + r] = s;
        }
    __syncthreads();
    if (t < 64) {
        float bs = 0.f;
        #pragma unroll
        for (int w2 = 0; w2 < 8; ++w2) bs += bsum_s[w2][t];
        down_s[t] = tot_s[t] - bs;
    }
    __syncthreads();

    #pragma unroll
    for (int ni = 0; ni < 4; ++ni)
        #pragma unroll
        for (int r = 0; r < 4; ++r) {
            int row = ni * 16 + rgrp + r;
            bool sel = (wm_s[row] == 1) ? (ws < 4) : (ws >= 4);
            float tt = 0.f;
            if (sel) {
                float dwn = down_s[row];
                // sum_mi -log(x_mi) == -log(prod_mi x_mi); product stays normal.
                float prod = 1.f;
                #pragma unroll
                for (int mi = 0; mi < 4; ++mi) {
                    float pv = Ev[ni][mi][r];
                    prod *= pv / (pv + dwn + 1e-12f);
                }
                tt = -logf(prod);
            }
            tt += __shfl_xor(tt, 1, 64);
            tt += __shfl_xor(tt, 2, 64);
            tt += __shfl_xor(tt, 4, 64);
            tt += __shfl_xor(tt, 8, 64);
            if (colL == 0) wsum_s[ws][row] = tt;
        }
    __syncthreads();
    if (t < 64) {
        int i = tile * 64 + t;
        float s = 0.f;
        if (i < cnt) {
            #pragma unroll
            for (int w2 = 0; w2 < 8; ++w2) s += wsum_s[w2][t];
        }
        term_s[t] = s;
    }
    __syncthreads();
    if (t < 64) {
        float s = term_s[t];
        #pragma unroll
        for (int off = 1; off < 64; off <<= 1) s += __shfl_xor(s, off, 64);
        if (t == 0) {
            atomicAdd(&class_sum[c], s);
            __threadfence();
            int old = atomicAdd(done, 1);
            if (old == P2_BLOCKS - 1) {
                float loss = 0.f, kc = 0.f;
                for (int cc = 0; cc < C_; ++cc) {
                    int cn = ccnt[cc];
                    float sc = atomicAdd(&class_sum[cc], 0.f);
                    if (cn > 0) { loss += sc / ((float)cn * (float)S_); kc += 1.f; }
                }
                out[0] = loss / fmaxf(kc, 1.f);
            }
        }
    }
}

extern "C" void kernel_launch(void* const* d_in, const int* in_sizes, int n_in,
                              void* d_out, int out_size, void* d_ws, size_t ws_size,
                              hipStream_t stream) {
    const float* mem    = (const float*)d_in[0];
    const float* pred   = (const float*)d_in[1];
    const int*   labels = (const int*)  d_in[2];
    const int*   mask   = (const int*)  d_in[3];
    const int*   wmem   = (const int*)  d_in[4];
    float* out = (float*)d_out;

    float* ws = (float*)d_ws;
    float* totpart4  = ws;                            // 152*NP_ = 2,860,032 floats
    int*   ctrl      = (int*)(ws + 2860032);          // 40 words
    int*   ccnt      = ctrl;                          // 19
    float* class_sum = (float*)(ctrl + 19);           // 19
    int*   done      = ctrl + 38;                     // 1
    int*   pix       = (int*)(ws + 2860072);          // 19*N_ = 311,296 ints
    int*   slotmap   = (int*)(ws + 3171368);          // N_ = 16,384 ints
    __hip_bfloat16* A16c = (__hip_bfloat16*)(ws + 3187752);   // NP_*256 bf16 (compact)
    __hip_bfloat16* B16  = (__hip_bfloat16*)(ws + 5596200);   // M_*256 bf16 (frag order)

    hipMemsetAsync(ctrl, 0, 40 * sizeof(int), stream);

    k_bucket<<<N_ / 256, 256, 0, stream>>>(labels, mask, ccnt, pix, slotmap);

    k_prep<<<PREP_TOTAL, 256, 0, stream>>>(pred, mem, A16c, B16, ccnt, slotmap);

    k_pass1<<<GEMM_BLKS, 512, 0, stream>>>(A16c, B16, ccnt, totpart4);

    dim3 g2(C_, 16);
    k_pass2<<<g2, 512, 0, stream>>>(A16c, B16, ccnt, pix, totpart4, wmem,
                                    class_sum, done, out);
}

// Round 11
// 171.991 us; speedup vs baseline: 1.5449x; 1.5449x over previous
//
#include <hip/hip_runtime.h>
#include <hip/hip_bf16.h>
#include <math.h>

#define B_ 4
#define F_ 256
#define C_ 19
#define S_ 256
#define N_ 16384
#define M_ 9728
#define MT_ 38           // m-tiles (256 cols each) in pass1
#define NP_ 18816        // totpart slot capacity (>= any padded_total)
#define PREP_PRED 256
#define PREP_TOTAL 2688  // 256 pred + 2432 mem
#define GEMM_BLKS 512
#define P2_BLOCKS (C_ * 16)

typedef __bf16 bf16_t;
typedef bf16_t bf16x8 __attribute__((ext_vector_type(8)));
typedef float floatx4 __attribute__((ext_vector_type(4)));

#define AS1 __attribute__((address_space(1)))
#define AS3 __attribute__((address_space(3)))

// Fragment-order layout: element (row, f) lives at
//   ((row>>4)*8 + (f>>5))*512 + ((f>>3)&3)*128 + (row&15)*8 + (f&7)
// For 64-aligned panels this equals panel_base*256 + 8*k with k the linear
// 16B-chunk index -> global_load_lds can stage panels linearly.
__device__ inline size_t fragoff(int row, int f) {
    return ((size_t)((row >> 4) * 8 + (f >> 5))) * 512
         + (size_t)((((f >> 3) & 3) * 128) + ((row & 15) * 8) + (f & 7));
}

// ---------------- kernel 0: bucketing + inverse slot map ----------
// ctrl zeroed by hipMemsetAsync before this kernel.
__global__ __launch_bounds__(256) void k_bucket(const int* __restrict__ labels,
                                                const int* __restrict__ mask,
                                                int* __restrict__ ccnt,
                                                int* __restrict__ pix,
                                                int* __restrict__ slotmap) {
    __shared__ int hist[C_], base_s[C_], cur[C_];
    int t = threadIdx.x;
    int n0 = blockIdx.x * 256;
    if (t < C_) { hist[t] = 0; cur[t] = 0; }
    __syncthreads();
    int myc = labels[n0 + t];
    int mym = mask[n0 + t];
    if (mym) atomicAdd(&hist[myc], 1);
    __syncthreads();
    if (t < C_) base_s[t] = atomicAdd(&ccnt[t], hist[t]);
    __syncthreads();
    int sm = -1;
    if (mym) {
        int o = atomicAdd(&cur[myc], 1);
        int pos = base_s[myc] + o;
        pix[myc * N_ + pos] = n0 + t;
        sm = (myc << 16) | pos;
    }
    slotmap[n0 + t] = sm;
}

// ---------------- kernel 1: prep -> compact A16c (masked only, 64-padded) + B16 ----------
// B16 entries scaled by 2.0 (exponent bump, exact in bf16): acc = 2*cos
// directly, so epilogue exp is __expf(acc) with no runtime scale mul.
__global__ __launch_bounds__(256) void k_prep(const float* __restrict__ pred,
                                              const float* __restrict__ mem,
                                              __hip_bfloat16* __restrict__ A16c,
                                              __hip_bfloat16* __restrict__ B16,
                                              const int* __restrict__ ccnt,
                                              const int* __restrict__ slotmap) {
    int bid = blockIdx.x;
    int t = threadIdx.x;
    if (bid < PREP_PRED) {
        __shared__ float part[4][64];
        __shared__ float invf_s[64];
        __shared__ int pre_s[C_];
        int b = bid >> 6, hw0 = (bid & 63) * 64;
        int j = t & 63, q = t >> 6;
        int n0 = b * 4096 + hw0;

        if (t < C_) {                       // 64-padded class prefix (ccnt final)
            int pre = 0;
            for (int cc = 0; cc < t; ++cc) pre += (ccnt[cc] + 63) & ~63;
            pre_s[t] = pre;
        }

        const float* base = pred + ((size_t)b * F_ + q * 64) * 4096 + hw0 + j;
        float v[64];
        float s = 0.f;
        #pragma unroll
        for (int i = 0; i < 64; ++i) {
            float x = base[(size_t)i * 4096];
            v[i] = x;
            s += x * x;
        }
        part[q][j] = s;
        __syncthreads();
        if (t < 64) invf_s[t] = 1.0f / sqrtf(part[0][t] + part[1][t] + part[2][t] + part[3][t]);
        __syncthreads();
        int sm = slotmap[n0 + j];
        if (sm >= 0) {
            int slot = pre_s[sm >> 16] + (sm & 0xffff);
            float invf = invf_s[j];
            #pragma unroll
            for (int c = 0; c < 8; ++c) {
                int f = q * 64 + c * 8;
                __hip_bfloat16 tmp[8];
                #pragma unroll
                for (int u = 0; u < 8; ++u) tmp[u] = __float2bfloat16(v[c * 8 + u] * invf);
                *(float4*)&A16c[fragoff(slot, f)] = *(float4*)tmp;
            }
        }
    } else {
        int row  = (bid - PREP_PRED) * 4 + (t >> 6);
        int lane = t & 63;
        float4 a = ((const float4*)(mem + (size_t)row * F_))[lane];
        float s = a.x*a.x + a.y*a.y + a.z*a.z + a.w*a.w;
        #pragma unroll
        for (int off = 32; off; off >>= 1) s += __shfl_xor(s, off, 64);
        float invm = 2.0f / sqrtf(s);          // fold exp scale (exact in bf16)
        __hip_bfloat16 tmp[4];
        tmp[0] = __float2bfloat16(a.x * invm);
        tmp[1] = __float2bfloat16(a.y * invm);
        tmp[2] = __float2bfloat16(a.z * invm);
        tmp[3] = __float2bfloat16(a.w * invm);
        *(float2*)&B16[fragoff(row, lane * 4)] = *(float2*)tmp;
    }
}

// ---------------- kernel 2: pass-1 GEMM over compact slots ----------
// R9 decomposition (balanced contiguous mt ranges), R2-proven epilogue:
// per-wave direct global stores + raw s_barrier per mt. The barrier is the
// cross-block L2 phase-lock for the B stream (R10 removed it: FETCH 35->375MB,
// pass1 59->152us). No vmcnt/lgkm drain -> B prefetches stay in flight.
__global__ __launch_bounds__(512, 4) void k_pass1(const __hip_bfloat16* __restrict__ A16c,
                                                  const __hip_bfloat16* __restrict__ B16,
                                                  const int* __restrict__ ccnt,
                                                  float* __restrict__ totpart4) {
    __shared__ __hip_bfloat16 As[128 * 256];     // 64 KB
    int bid = blockIdx.x;
    int t = threadIdx.x;
    int w = t >> 6, lane = t & 63;
    int nh = w & 1, mq = w >> 1;

    int padded_total = 0;
    #pragma unroll
    for (int cc = 0; cc < C_; ++cc) padded_total += (ccnt[cc] + 63) & ~63;
    int nt_total = (padded_total + 127) >> 7;
    if (nt_total == 0) return;
    int nchunk = GEMM_BLKS / nt_total;
    if (nchunk > MT_) nchunk = MT_;
    if (nchunk < 1) nchunk = 1;
    if (bid >= nt_total * nchunk) return;
    int panel = bid % nt_total;
    int chunk = bid / nt_total;
    int slot0 = panel << 7;
    int mt_lo = (chunk * MT_) / nchunk;
    int mt_hi = ((chunk + 1) * MT_) / nchunk;

    // stage A panel: 64 KB linear from compact buffer
    {
        const __hip_bfloat16* src = A16c + ((size_t)slot0 << 8) + w * 4096 + lane * 8;
        __hip_bfloat16* dst = &As[w * 4096];
        #pragma unroll
        for (int i = 0; i < 8; ++i)
            __builtin_amdgcn_global_load_lds((const AS1 unsigned int*)(src + i * 512),
                                             (AS3 unsigned int*)(dst + i * 512), 16, 0, 0);
    }
    __syncthreads();

    int colL = lane & 15, rgrp = (lane >> 4) * 4;
    for (int mt = mt_lo; mt < mt_hi; ++mt) {
        floatx4 acc[4][4];
        #pragma unroll
        for (int i = 0; i < 4; ++i)
            #pragma unroll
            for (int j2 = 0; j2 < 4; ++j2) acc[i][j2] = (floatx4){0.f, 0.f, 0.f, 0.f};

        const bf16x8* Bp = (const bf16x8*)B16 + ((size_t)(mt * 16 + mq * 4) * 8) * 64 + lane;

        #pragma unroll
        for (int kt = 0; kt < 8; ++kt) {
            bf16x8 af[4], bfr[4];
            #pragma unroll
            for (int ni = 0; ni < 4; ++ni)
                af[ni] = *(const bf16x8*)&As[((nh * 4 + ni) * 8 + kt) * 512 + lane * 8];
            #pragma unroll
            for (int mi = 0; mi < 4; ++mi)
                bfr[mi] = Bp[(size_t)(mi * 8 + kt) * 64];
            __builtin_amdgcn_s_setprio(1);
            #pragma unroll
            for (int ni = 0; ni < 4; ++ni)
                #pragma unroll
                for (int mi = 0; mi < 4; ++mi)
                    acc[ni][mi] = __builtin_amdgcn_mfma_f32_16x16x32_bf16(af[ni], bfr[mi], acc[ni][mi], 0, 0, 0);
            __builtin_amdgcn_s_setprio(0);
        }

        // epilogue: E = exp(acc) (scale folded into B) -> per-wave row sums ->
        // direct global store (no LDS combine)
        float racc[4][4];
        #pragma unroll
        for (int ni = 0; ni < 4; ++ni)
            #pragma unroll
            for (int r = 0; r < 4; ++r) racc[ni][r] = 0.f;
        #pragma unroll
        for (int ni = 0; ni < 4; ++ni)
            #pragma unroll
            for (int mi = 0; mi < 4; ++mi)
                #pragma unroll
                for (int r = 0; r < 4; ++r)
                    racc[ni][r] += __expf(acc[ni][mi][r]);

        float* outp = totpart4 + (size_t)(mt * 4 + mq) * NP_ + slot0 + nh * 64;
        #pragma unroll
        for (int ni = 0; ni < 4; ++ni)
            #pragma unroll
            for (int r = 0; r < 4; ++r) {
                float s = racc[ni][r];
                s += __shfl_xor(s, 1, 64);
                s += __shfl_xor(s, 2, 64);
                s += __shfl_xor(s, 4, 64);
                s += __shfl_xor(s, 8, 64);
                if (colL == 0) outp[ni * 16 + rgrp + r] = s;
            }
        // raw barrier: cross-block/wave mt phase-lock for B L2 reuse; no drain
        __builtin_amdgcn_s_barrier();
    }
}

// ---------------- kernel 3: pass-2 own-class recompute + terms + final ----------------
__global__ __launch_bounds__(512) void k_pass2(const __hip_bfloat16* __restrict__ A16c,
                                               const __hip_bfloat16* __restrict__ B16,
                                               const int* __restrict__ ccnt,
                                               const int* __restrict__ pix,
                                               const float* __restrict__ totpart4,
                                               const int* __restrict__ wmem,
                                               float* __restrict__ class_sum,
                                               int* __restrict__ done,
                                               float* __restrict__ out) {
    __shared__ __hip_bfloat16 As[64 * 256];   // 32 KB, fragment order
    __shared__ float tot_s[64];
    __shared__ int wm_s[64];
    __shared__ float bsum_s[8][64];
    __shared__ float wsum_s[8][64];
    __shared__ float down_s[64];
    __shared__ float term_s[64];

    int c = blockIdx.x, tile = blockIdx.y;
    int cnt = ccnt[c];
    int t = threadIdx.x, ws = t >> 6, lane = t & 63;

    if (tile * 64 >= cnt) {                    // empty tile: still hit the counter
        if (t == 0) {
            __threadfence();
            int old = atomicAdd(done, 1);
            if (old == P2_BLOCKS - 1) {
                float loss = 0.f, kc = 0.f;
                for (int cc = 0; cc < C_; ++cc) {
                    int cn = ccnt[cc];
                    float sc = atomicAdd(&class_sum[cc], 0.f);
                    if (cn > 0) { loss += sc / ((float)cn * (float)S_); kc += 1.f; }
                }
                out[0] = loss / fmaxf(kc, 1.f);
            }
        }
        return;
    }

    // compact-slot base (64-padded prefix) of this tile
    int pre = 0;
    #pragma unroll
    for (int cc = 0; cc < C_; ++cc) if (cc < c) pre += (ccnt[cc] + 63) & ~63;
    int slot0 = pre + tile * 64;

    // stage A tile: 32 KB linear from compact buffer (issued first, overlaps
    // the scattered wmem/totpart reads below)
    {
        const __hip_bfloat16* src = A16c + ((size_t)slot0 << 8) + t * 8;
        __hip_bfloat16* dst = &As[t * 8];
        #pragma unroll
        for (int i = 0; i < 4; ++i)
            __builtin_amdgcn_global_load_lds((const AS1 unsigned int*)(src + i * 4096),
                                             (AS3 unsigned int*)(dst + i * 4096), 16, 0, 0);
    }

    if (t < 64) {
        int i = tile * 64 + t;
        int p = pix[c * N_ + (i < cnt ? i : 0)];
        wm_s[t] = wmem[p];
    }

    // inline total: 8 threads per pixel sum the 152 partial slots (contiguous)
    {
        int px = t >> 3, g = t & 7;
        float s = 0.f;
        for (int i = g; i < MT_ * 4; i += 8) s += totpart4[(size_t)i * NP_ + slot0 + px];
        s += __shfl_xor(s, 1, 64);
        s += __shfl_xor(s, 2, 64);
        s += __shfl_xor(s, 4, 64);
        if (g == 0) tot_s[px] = s;
    }
    __syncthreads();

    floatx4 acc[4][4];
    #pragma unroll
    for (int i = 0; i < 4; ++i)
        #pragma unroll
        for (int j = 0; j < 4; ++j) acc[i][j] = (floatx4){0.f, 0.f, 0.f, 0.f};

    const bf16x8* Bp = (const bf16x8*)B16 + ((size_t)(c * 32 + ws * 4) * 8) * 64 + lane;
    #pragma unroll
    for (int kt = 0; kt < 8; ++kt) {
        bf16x8 af[4], bfr[4];
        #pragma unroll
        for (int ni = 0; ni < 4; ++ni)
            af[ni] = *(const bf16x8*)&As[(ni * 8 + kt) * 512 + lane * 8];
        #pragma unroll
        for (int mi = 0; mi < 4; ++mi) bfr[mi] = Bp[(size_t)(mi * 8 + kt) * 64];
        #pragma unroll
        for (int ni = 0; ni < 4; ++ni)
            #pragma unroll
            for (int mi = 0; mi < 4; ++mi)
                acc[ni][mi] = __builtin_amdgcn_mfma_f32_16x16x32_bf16(af[ni], bfr[mi], acc[ni][mi], 0, 0, 0);
    }

    int colL = lane & 15, rgrp = (lane >> 4) * 4;
    float Ev[4][4][4];
    #pragma unroll
    for (int ni = 0; ni < 4; ++ni)
        #pragma unroll
        for (int mi = 0; mi < 4; ++mi)
            #pragma unroll
            for (int r = 0; r < 4; ++r)
                Ev[ni][mi][r] = __expf(acc[ni][mi][r]);

    #pragma unroll
    for (int ni = 0; ni < 4; ++ni)
        #pragma unroll
        for (int r = 0; r < 4; ++r) {
            float s = Ev[ni][0][r] + Ev[ni][1][r] + Ev[ni][2][r] + Ev[ni][3][r];
            s += __shfl_xor(s, 1, 64);
            s += __shfl_xor(s, 2, 64);
            s += __shfl_xor(s, 4, 64);
            s += __shfl_xor(s, 8, 64);
            if (colL == 0) bsum_s[ws][ni * 16 + rgrp + r] = s;
        }
    __syncthreads();
    if (t < 64) {
        float bs = 0.f;
        #pragma unroll
        for (int w2 = 0; w2 < 8; ++w2) bs += bsum_s[w2][t];
        down_s[t] = tot_s[t] - bs;
    }
    __syncthreads();

    #pragma unroll
    for (int ni = 0; ni < 4; ++ni)
        #pragma unroll
        for (int r = 0; r < 4; ++r) {
            int row = ni * 16 + rgrp + r;
            bool sel = (wm_s[row] == 1) ? (ws < 4) : (ws >= 4);
            float tt = 0.f;
            if (sel) {
                float dwn = down_s[row];
                // sum_mi -log(x_mi) == -log(prod_mi x_mi); product stays normal.
                float prod = 1.f;
                #pragma unroll
                for (int mi = 0; mi < 4; ++mi) {
                    float pv = Ev[ni][mi][r];
                    prod *= pv / (pv + dwn + 1e-12f);
                }
                tt = -logf(prod);
            }
            tt += __shfl_xor(tt, 1, 64);
            tt += __shfl_xor(tt, 2, 64);
            tt += __shfl_xor(tt, 4, 64);
            tt += __shfl_xor(tt, 8, 64);
            if (colL == 0) wsum_s[ws][row] = tt;
        }
    __syncthreads();
    if (t < 64) {
        int i = tile * 64 + t;
        float s = 0.f;
        if (i < cnt) {
            #pragma unroll
            for (int w2 = 0; w2 < 8; ++w2) s += wsum_s[w2][t];
        }
        term_s[t] = s;
    }
    __syncthreads();
    if (t < 64) {
        float s = term_s[t];
        #pragma unroll
        for (int off = 1; off < 64; off <<= 1) s += __shfl_xor(s, off, 64);
        if (t == 0) {
            atomicAdd(&class_sum[c], s);
            __threadfence();
            int old = atomicAdd(done, 1);
            if (old == P2_BLOCKS - 1) {
                float loss = 0.f, kc = 0.f;
                for (int cc = 0; cc < C_; ++cc) {
                    int cn = ccnt[cc];
                    float sc = atomicAdd(&class_sum[cc], 0.f);
                    if (cn > 0) { loss += sc / ((float)cn * (float)S_); kc += 1.f; }
                }
                out[0] = loss / fmaxf(kc, 1.f);
            }
        }
    }
}

extern "C" void kernel_launch(void* const* d_in, const int* in_sizes, int n_in,
                              void* d_out, int out_size, void* d_ws, size_t ws_size,
                              hipStream_t stream) {
    const float* mem    = (const float*)d_in[0];
    const float* pred   = (const float*)d_in[1];
    const int*   labels = (const int*)  d_in[2];
    const int*   mask   = (const int*)  d_in[3];
    const int*   wmem   = (const int*)  d_in[4];
    float* out = (float*)d_out;

    float* ws = (float*)d_ws;
    float* totpart4  = ws;                            // 152*NP_ = 2,860,032 floats
    int*   ctrl      = (int*)(ws + 2860032);          // 40 words
    int*   ccnt      = ctrl;                          // 19
    float* class_sum = (float*)(ctrl + 19);           // 19
    int*   done      = ctrl + 38;                     // 1
    int*   pix       = (int*)(ws + 2860072);          // 19*N_ = 311,296 ints
    int*   slotmap   = (int*)(ws + 3171368);          // N_ = 16,384 ints
    __hip_bfloat16* A16c = (__hip_bfloat16*)(ws + 3187752);   // NP_*256 bf16 (compact)
    __hip_bfloat16* B16  = (__hip_bfloat16*)(ws + 5596200);   // M_*256 bf16 (frag order)

    hipMemsetAsync(ctrl, 0, 40 * sizeof(int), stream);

    k_bucket<<<N_ / 256, 256, 0, stream>>>(labels, mask, ccnt, pix, slotmap);

    k_prep<<<PREP_TOTAL, 256, 0, stream>>>(pred, mem, A16c, B16, ccnt, slotmap);

    k_pass1<<<GEMM_BLKS, 512, 0, stream>>>(A16c, B16, ccnt, totpart4);

    dim3 g2(C_, 16);
    k_pass2<<<g2, 512, 0, stream>>>(A16c, B16, ccnt, pix, totpart4, wmem,
                                    class_sum, done, out);
}

// Round 12
// 165.787 us; speedup vs baseline: 1.6028x; 1.0374x over previous
//
#include <hip/hip_runtime.h>
#include <hip/hip_bf16.h>
#include <math.h>

#define B_ 4
#define F_ 256
#define C_ 19
#define S_ 256
#define N_ 16384
#define M_ 9728
#define MT_ 38           // m-tiles (256 cols each) in pass1
#define NP_ 18816        // totpart slot capacity (>= any padded_total)
#define PREP_PRED 256
#define PREP_TOTAL 2688  // 256 pred + 2432 mem
#define GEMM_BLKS 512
#define P2_BLOCKS (C_ * 16)

typedef __bf16 bf16_t;
typedef bf16_t bf16x8 __attribute__((ext_vector_type(8)));
typedef float floatx4 __attribute__((ext_vector_type(4)));

#define AS1 __attribute__((address_space(1)))
#define AS3 __attribute__((address_space(3)))

// Fragment-order layout: element (row, f) lives at
//   ((row>>4)*8 + (f>>5))*512 + ((f>>3)&3)*128 + (row&15)*8 + (f&7)
// For 64-aligned panels this equals panel_base*256 + 8*k with k the linear
// 16B-chunk index -> global_load_lds can stage panels linearly.
__device__ inline size_t fragoff(int row, int f) {
    return ((size_t)((row >> 4) * 8 + (f >> 5))) * 512
         + (size_t)((((f >> 3) & 3) * 128) + ((row & 15) * 8) + (f & 7));
}

// ---------------- kernel 0: bucketing + inverse slot map ----------
// ctrl zeroed by hipMemsetAsync before this kernel.
__global__ __launch_bounds__(256) void k_bucket(const int* __restrict__ labels,
                                                const int* __restrict__ mask,
                                                int* __restrict__ ccnt,
                                                int* __restrict__ pix,
                                                int* __restrict__ slotmap) {
    __shared__ int hist[C_], base_s[C_], cur[C_];
    int t = threadIdx.x;
    int n0 = blockIdx.x * 256;
    if (t < C_) { hist[t] = 0; cur[t] = 0; }
    __syncthreads();
    int myc = labels[n0 + t];
    int mym = mask[n0 + t];
    if (mym) atomicAdd(&hist[myc], 1);
    __syncthreads();
    if (t < C_) base_s[t] = atomicAdd(&ccnt[t], hist[t]);
    __syncthreads();
    int sm = -1;
    if (mym) {
        int o = atomicAdd(&cur[myc], 1);
        int pos = base_s[myc] + o;
        pix[myc * N_ + pos] = n0 + t;
        sm = (myc << 16) | pos;
    }
    slotmap[n0 + t] = sm;
}

// ---------------- kernel 1: prep -> compact A16c (masked only, 64-padded) + B16 ----------
// B16 entries scaled by 2.0 (exponent bump, exact in bf16): acc = 2*cos
// directly, so epilogue exp is __expf(acc) with no runtime scale mul.
__global__ __launch_bounds__(256) void k_prep(const float* __restrict__ pred,
                                              const float* __restrict__ mem,
                                              __hip_bfloat16* __restrict__ A16c,
                                              __hip_bfloat16* __restrict__ B16,
                                              const int* __restrict__ ccnt,
                                              const int* __restrict__ slotmap) {
    int bid = blockIdx.x;
    int t = threadIdx.x;
    if (bid < PREP_PRED) {
        __shared__ float part[4][64];
        __shared__ float invf_s[64];
        __shared__ int pre_s[C_];
        int b = bid >> 6, hw0 = (bid & 63) * 64;
        int j = t & 63, q = t >> 6;
        int n0 = b * 4096 + hw0;

        if (t < C_) {                       // 64-padded class prefix (ccnt final)
            int pre = 0;
            for (int cc = 0; cc < t; ++cc) pre += (ccnt[cc] + 63) & ~63;
            pre_s[t] = pre;
        }

        const float* base = pred + ((size_t)b * F_ + q * 64) * 4096 + hw0 + j;
        float v[64];
        float s = 0.f;
        #pragma unroll
        for (int i = 0; i < 64; ++i) {
            float x = base[(size_t)i * 4096];
            v[i] = x;
            s += x * x;
        }
        part[q][j] = s;
        __syncthreads();
        if (t < 64) invf_s[t] = 1.0f / sqrtf(part[0][t] + part[1][t] + part[2][t] + part[3][t]);
        __syncthreads();
        int sm = slotmap[n0 + j];
        if (sm >= 0) {
            int slot = pre_s[sm >> 16] + (sm & 0xffff);
            float invf = invf_s[j];
            #pragma unroll
            for (int c = 0; c < 8; ++c) {
                int f = q * 64 + c * 8;
                __hip_bfloat16 tmp[8];
                #pragma unroll
                for (int u = 0; u < 8; ++u) tmp[u] = __float2bfloat16(v[c * 8 + u] * invf);
                *(float4*)&A16c[fragoff(slot, f)] = *(float4*)tmp;
            }
        }
    } else {
        int row  = (bid - PREP_PRED) * 4 + (t >> 6);
        int lane = t & 63;
        float4 a = ((const float4*)(mem + (size_t)row * F_))[lane];
        float s = a.x*a.x + a.y*a.y + a.z*a.z + a.w*a.w;
        #pragma unroll
        for (int off = 32; off; off >>= 1) s += __shfl_xor(s, off, 64);
        float invm = 2.0f / sqrtf(s);          // fold exp scale (exact in bf16)
        __hip_bfloat16 tmp[4];
        tmp[0] = __float2bfloat16(a.x * invm);
        tmp[1] = __float2bfloat16(a.y * invm);
        tmp[2] = __float2bfloat16(a.z * invm);
        tmp[3] = __float2bfloat16(a.w * invm);
        *(float2*)&B16[fragoff(row, lane * 4)] = *(float2*)tmp;
    }
}

// ---------------- kernel 2: pass-1 GEMM over compact slots (R9 structure) ----------
// nt_total = ceil(padded_total/128) panels; nchunk = min(512/nt_total, 38).
// Balanced contiguous mt ranges. A panel staged linearly via global_load_lds
// (8 waves of 64x64, acc[4][4] -- exactly fills the 128-reg budget at
// __launch_bounds__(512,4), which 2 LDS-bound blocks/CU require).
// lgkm-only combine barrier per mt: LDS combine visible, B prefetches stay in
// flight, AND the barrier phase-locks blocks through mts for B L2 reuse
// (R10 removed it: FETCH 35->375 MB, pass1 59->152 us).
__global__ __launch_bounds__(512, 4) void k_pass1(const __hip_bfloat16* __restrict__ A16c,
                                                  const __hip_bfloat16* __restrict__ B16,
                                                  const int* __restrict__ ccnt,
                                                  float* __restrict__ totpart) {
    __shared__ __hip_bfloat16 As[128 * 256];     // 64 KB
    __shared__ float totals_s[2][4][128];        // 4 KB (double-buffered)
    int bid = blockIdx.x;
    int t = threadIdx.x;
    int w = t >> 6, lane = t & 63;
    int nh = w & 1, mq = w >> 1;

    int padded_total = 0;
    #pragma unroll
    for (int cc = 0; cc < C_; ++cc) padded_total += (ccnt[cc] + 63) & ~63;
    int nt_total = (padded_total + 127) >> 7;
    if (nt_total == 0) return;
    int nchunk = GEMM_BLKS / nt_total;
    if (nchunk > MT_) nchunk = MT_;
    if (nchunk < 1) nchunk = 1;
    if (bid >= nt_total * nchunk) return;
    int panel = bid % nt_total;
    int chunk = bid / nt_total;
    int slot0 = panel << 7;
    int mt_lo = (chunk * MT_) / nchunk;
    int mt_hi = ((chunk + 1) * MT_) / nchunk;

    // stage A panel: 64 KB linear from compact buffer
    {
        const __hip_bfloat16* src = A16c + ((size_t)slot0 << 8) + w * 4096 + lane * 8;
        __hip_bfloat16* dst = &As[w * 4096];
        #pragma unroll
        for (int i = 0; i < 8; ++i)
            __builtin_amdgcn_global_load_lds((const AS1 unsigned int*)(src + i * 512),
                                             (AS3 unsigned int*)(dst + i * 512), 16, 0, 0);
    }
    __syncthreads();

    int colL = lane & 15, rgrp = (lane >> 4) * 4;
    int p = 0;
    for (int mt = mt_lo; mt < mt_hi; ++mt, p ^= 1) {
        floatx4 acc[4][4];
        #pragma unroll
        for (int i = 0; i < 4; ++i)
            #pragma unroll
            for (int j2 = 0; j2 < 4; ++j2) acc[i][j2] = (floatx4){0.f, 0.f, 0.f, 0.f};

        const bf16x8* Bp = (const bf16x8*)B16 + ((size_t)(mt * 16 + mq * 4) * 8) * 64 + lane;

        #pragma unroll
        for (int kt = 0; kt < 8; ++kt) {
            bf16x8 af[4], bfr[4];
            #pragma unroll
            for (int ni = 0; ni < 4; ++ni)
                af[ni] = *(const bf16x8*)&As[((nh * 4 + ni) * 8 + kt) * 512 + lane * 8];
            #pragma unroll
            for (int mi = 0; mi < 4; ++mi)
                bfr[mi] = Bp[(size_t)(mi * 8 + kt) * 64];
            __builtin_amdgcn_s_setprio(1);
            #pragma unroll
            for (int ni = 0; ni < 4; ++ni)
                #pragma unroll
                for (int mi = 0; mi < 4; ++mi)
                    acc[ni][mi] = __builtin_amdgcn_mfma_f32_16x16x32_bf16(af[ni], bfr[mi], acc[ni][mi], 0, 0, 0);
            __builtin_amdgcn_s_setprio(0);
        }

        // epilogue: E = exp(acc) (scale folded into B) -> wave row-sums ->
        // LDS combine over the 4 mq waves
        float racc[4][4];
        #pragma unroll
        for (int ni = 0; ni < 4; ++ni)
            #pragma unroll
            for (int r = 0; r < 4; ++r) racc[ni][r] = 0.f;
        #pragma unroll
        for (int ni = 0; ni < 4; ++ni)
            #pragma unroll
            for (int mi = 0; mi < 4; ++mi)
                #pragma unroll
                for (int r = 0; r < 4; ++r)
                    racc[ni][r] += __expf(acc[ni][mi][r]);

        #pragma unroll
        for (int ni = 0; ni < 4; ++ni)
            #pragma unroll
            for (int r = 0; r < 4; ++r) {
                float s = racc[ni][r];
                s += __shfl_xor(s, 1, 64);
                s += __shfl_xor(s, 2, 64);
                s += __shfl_xor(s, 4, 64);
                s += __shfl_xor(s, 8, 64);
                if (colL == 0) totals_s[p][mq][nh * 64 + ni * 16 + rgrp + r] = s;
            }
        // lgkm-only barrier: LDS writes visible, global (B) loads stay in flight
        asm volatile("s_waitcnt lgkmcnt(0)\n\ts_barrier" ::: "memory");
        if (t < 128)
            totpart[(size_t)mt * NP_ + slot0 + t] =
                totals_s[p][0][t] + totals_s[p][1][t] + totals_s[p][2][t] + totals_s[p][3][t];
    }
}

// ---------------- kernel 3: pass-2 own-class recompute + terms + final ----------------
__global__ __launch_bounds__(512) void k_pass2(const __hip_bfloat16* __restrict__ A16c,
                                               const __hip_bfloat16* __restrict__ B16,
                                               const int* __restrict__ ccnt,
                                               const int* __restrict__ pix,
                                               const float* __restrict__ totpart,
                                               const int* __restrict__ wmem,
                                               float* __restrict__ class_sum,
                                               int* __restrict__ done,
                                               float* __restrict__ out) {
    __shared__ __hip_bfloat16 As[64 * 256];   // 32 KB, fragment order
    __shared__ float tot_s[64];
    __shared__ int wm_s[64];
    __shared__ float bsum_s[8][64];
    __shared__ float wsum_s[8][64];
    __shared__ float down_s[64];
    __shared__ float term_s[64];

    int c = blockIdx.x, tile = blockIdx.y;
    int cnt = ccnt[c];
    int t = threadIdx.x, ws = t >> 6, lane = t & 63;

    if (tile * 64 >= cnt) {                    // empty tile: still hit the counter
        if (t == 0) {
            __threadfence();
            int old = atomicAdd(done, 1);
            if (old == P2_BLOCKS - 1) {
                float loss = 0.f, kc = 0.f;
                for (int cc = 0; cc < C_; ++cc) {
                    int cn = ccnt[cc];
                    float sc = atomicAdd(&class_sum[cc], 0.f);
                    if (cn > 0) { loss += sc / ((float)cn * (float)S_); kc += 1.f; }
                }
                out[0] = loss / fmaxf(kc, 1.f);
            }
        }
        return;
    }

    // compact-slot base (64-padded prefix) of this tile
    int pre = 0;
    #pragma unroll
    for (int cc = 0; cc < C_; ++cc) if (cc < c) pre += (ccnt[cc] + 63) & ~63;
    int slot0 = pre + tile * 64;

    // stage A tile: 32 KB linear from compact buffer (issued first, overlaps
    // the scattered wmem/totpart reads below)
    {
        const __hip_bfloat16* src = A16c + ((size_t)slot0 << 8) + t * 8;
        __hip_bfloat16* dst = &As[t * 8];
        #pragma unroll
        for (int i = 0; i < 4; ++i)
            __builtin_amdgcn_global_load_lds((const AS1 unsigned int*)(src + i * 4096),
                                             (AS3 unsigned int*)(dst + i * 4096), 16, 0, 0);
    }

    if (t < 64) {
        int i = tile * 64 + t;
        int p = pix[c * N_ + (i < cnt ? i : 0)];
        wm_s[t] = wmem[p];
    }

    // inline total: 8 threads per pixel sum the 38 partial slots (contiguous)
    {
        int px = t >> 3, g = t & 7;
        float s = 0.f;
        for (int i = g; i < MT_; i += 8) s += totpart[(size_t)i * NP_ + slot0 + px];
        s += __shfl_xor(s, 1, 64);
        s += __shfl_xor(s, 2, 64);
        s += __shfl_xor(s, 4, 64);
        if (g == 0) tot_s[px] = s;
    }
    __syncthreads();

    floatx4 acc[4][4];
    #pragma unroll
    for (int i = 0; i < 4; ++i)
        #pragma unroll
        for (int j = 0; j < 4; ++j) acc[i][j] = (floatx4){0.f, 0.f, 0.f, 0.f};

    const bf16x8* Bp = (const bf16x8*)B16 + ((size_t)(c * 32 + ws * 4) * 8) * 64 + lane;
    #pragma unroll
    for (int kt = 0; kt < 8; ++kt) {
        bf16x8 af[4], bfr[4];
        #pragma unroll
        for (int ni = 0; ni < 4; ++ni)
            af[ni] = *(const bf16x8*)&As[(ni * 8 + kt) * 512 + lane * 8];
        #pragma unroll
        for (int mi = 0; mi < 4; ++mi) bfr[mi] = Bp[(size_t)(mi * 8 + kt) * 64];
        #pragma unroll
        for (int ni = 0; ni < 4; ++ni)
            #pragma unroll
            for (int mi = 0; mi < 4; ++mi)
                acc[ni][mi] = __builtin_amdgcn_mfma_f32_16x16x32_bf16(af[ni], bfr[mi], acc[ni][mi], 0, 0, 0);
    }

    int colL = lane & 15, rgrp = (lane >> 4) * 4;
    float Ev[4][4][4];
    #pragma unroll
    for (int ni = 0; ni < 4; ++ni)
        #pragma unroll
        for (int mi = 0; mi < 4; ++mi)
            #pragma unroll
            for (int r = 0; r < 4; ++r)
                Ev[ni][mi][r] = __expf(acc[ni][mi][r]);

    #pragma unroll
    for (int ni = 0; ni < 4; ++ni)
        #pragma unroll
        for (int r = 0; r < 4; ++r) {
            float s = Ev[ni][0][r] + Ev[ni][1][r] + Ev[ni][2][r] + Ev[ni][3][r];
            s += __shfl_xor(s, 1, 64);
            s += __shfl_xor(s, 2, 64);
            s += __shfl_xor(s, 4, 64);
            s += __shfl_xor(s, 8, 64);
            if (colL == 0) bsum_s[ws][ni * 16 + rgrp + r] = s;
        }
    __syncthreads();
    if (t < 64) {
        float bs = 0.f;
        #pragma unroll
        for (int w2 = 0; w2 < 8; ++w2) bs += bsum_s[w2][t];
        down_s[t] = tot_s[t] - bs;
    }
    __syncthreads();

    #pragma unroll
    for (int ni = 0; ni < 4; ++ni)
        #pragma unroll
        for (int r = 0; r < 4; ++r) {
            int row = ni * 16 + rgrp + r;
            bool sel = (wm_s[row] == 1) ? (ws < 4) : (ws >= 4);
            float tt = 0.f;
            if (sel) {
                float dwn = down_s[row];
                // sum_mi -log(x_mi) == -log(prod_mi x_mi); product stays normal.
                float prod = 1.f;
                #pragma unroll
                for (int mi = 0; mi < 4; ++mi) {
                    float pv = Ev[ni][mi][r];
                    prod *= pv / (pv + dwn + 1e-12f);
                }
                tt = -logf(prod);
            }
            tt += __shfl_xor(tt, 1, 64);
            tt += __shfl_xor(tt, 2, 64);
            tt += __shfl_xor(tt, 4, 64);
            tt += __shfl_xor(tt, 8, 64);
            if (colL == 0) wsum_s[ws][row] = tt;
        }
    __syncthreads();
    if (t < 64) {
        int i = tile * 64 + t;
        float s = 0.f;
        if (i < cnt) {
            #pragma unroll
            for (int w2 = 0; w2 < 8; ++w2) s += wsum_s[w2][t];
        }
        term_s[t] = s;
    }
    __syncthreads();
    if (t < 64) {
        float s = term_s[t];
        #pragma unroll
        for (int off = 1; off < 64; off <<= 1) s += __shfl_xor(s, off, 64);
        if (t == 0) {
            atomicAdd(&class_sum[c], s);
            __threadfence();
            int old = atomicAdd(done, 1);
            if (old == P2_BLOCKS - 1) {
                float loss = 0.f, kc = 0.f;
                for (int cc = 0; cc < C_; ++cc) {
                    int cn = ccnt[cc];
                    float sc = atomicAdd(&class_sum[cc], 0.f);
                    if (cn > 0) { loss += sc / ((float)cn * (float)S_); kc += 1.f; }
                }
                out[0] = loss / fmaxf(kc, 1.f);
            }
        }
    }
}

extern "C" void kernel_launch(void* const* d_in, const int* in_sizes, int n_in,
                              void* d_out, int out_size, void* d_ws, size_t ws_size,
                              hipStream_t stream) {
    const float* mem    = (const float*)d_in[0];
    const float* pred   = (const float*)d_in[1];
    const int*   labels = (const int*)  d_in[2];
    const int*   mask   = (const int*)  d_in[3];
    const int*   wmem   = (const int*)  d_in[4];
    float* out = (float*)d_out;

    float* ws = (float*)d_ws;
    float* totpart   = ws;                            // 38*NP_ = 715,008 floats
    int*   ctrl      = (int*)(ws + 715008);           // 40 words
    int*   ccnt      = ctrl;                          // 19
    float* class_sum = (float*)(ctrl + 19);           // 19
    int*   done      = ctrl + 38;                     // 1
    int*   pix       = (int*)(ws + 715048);           // 19*N_ = 311,296 ints
    int*   slotmap   = (int*)(ws + 1026344);          // N_ = 16,384 ints
    __hip_bfloat16* A16c = (__hip_bfloat16*)(ws + 1042728);   // NP_*256 bf16 (compact)
    __hip_bfloat16* B16  = (__hip_bfloat16*)(ws + 3451176);   // M_*256 bf16 (frag order)

    hipMemsetAsync(ctrl, 0, 40 * sizeof(int), stream);

    k_bucket<<<N_ / 256, 256, 0, stream>>>(labels, mask, ccnt, pix, slotmap);

    k_prep<<<PREP_TOTAL, 256, 0, stream>>>(pred, mem, A16c, B16, ccnt, slotmap);

    k_pass1<<<GEMM_BLKS, 512, 0, stream>>>(A16c, B16, ccnt, totpart);

    dim3 g2(C_, 16);
    k_pass2<<<g2, 512, 0, stream>>>(A16c, B16, ccnt, pix, totpart, wmem,
                                    class_sum, done, out);
}